// Round 1
// baseline (245.695 us; speedup 1.0000x reference)
//
#include <hip/hip_runtime.h>

#define F_ALL 20000
#define FP    10000
#define BB    4
#define CC    64
#define KK    16
#define OO    128
#define NFACE (BB*FP)        // 40000
#define NELEM (BB*OO*FP)     // 5,120,000

// workspace layout (float offsets)
#define WS_AGG 0
#define WS_MT  (NFACE*64)        // 2,560,000  (M^T stored as MT[j][i] = M[i][j])
#define WS_V0  (WS_MT + 4096)
#define WS_W0  (WS_V0 + 64)
#define WS_C0  (WS_W0 + 64)
#define WS_S1  (WS_C0 + 16)      // sum_y[128]
#define WS_S2  (WS_S1 + 128)     // sum_y2[128]

__device__ __forceinline__ float lanebc(float v, int l) {
    return __uint_as_float(__builtin_amdgcn_readlane(__float_as_uint(v), l));
}

// ---------------- K1: transpose fea [B,C,F] -> feaT [B,F,64] ----------------
__global__ __launch_bounds__(256) void k_transpose(const float* __restrict__ fea,
                                                   float* __restrict__ feaT) {
    __shared__ float tile[64][65];
    int bb = blockIdx.x / 313;
    int tb = blockIdx.x % 313;
    int fbase = tb * 64;
    int tid = threadIdx.x;
    int x  = tid & 63;
    int y0 = tid >> 6;
    int f = fbase + x;
    if (f < F_ALL) {
#pragma unroll
        for (int i = 0; i < 16; i++) {
            int c = y0 + i * 4;
            tile[c][x] = fea[((long)bb * CC + c) * F_ALL + f];
        }
    }
    __syncthreads();
#pragma unroll
    for (int i = 0; i < 16; i++) {
        int fr = y0 + i * 4;
        int ff = fbase + fr;
        if (ff < F_ALL)
            feaT[((long)bb * F_ALL + ff) * 64 + x] = tile[x][fr];
    }
}

// ---------------- K2: precompute M^T, v0, w0, c0; zero stats ----------------
__global__ __launch_bounds__(256) void k_precompute(const float* __restrict__ Wk,
                                                    const float* __restrict__ bk,
                                                    const float* __restrict__ Wq,
                                                    const float* __restrict__ bq,
                                                    float* __restrict__ ws) {
    int idx = blockIdx.x * 256 + threadIdx.x;   // 0..4095
    int j = idx >> 6, i = idx & 63;
    float acc = 0.f;
#pragma unroll 8
    for (int o = 0; o < 128; o++) acc += Wq[o * 64 + i] * Wk[o * 64 + j];
    ws[WS_MT + idx] = acc;                       // MT[j][i] = M[i][j]
    if (blockIdx.x == 0) {
        int t = threadIdx.x;
        if (t < 64) {
            float a = 0.f, w = 0.f;
            for (int o = 0; o < 128; o++) {
                a += Wq[o * 64 + t] * bk[o];
                w += Wk[o * 64 + t] * bq[o];
            }
            ws[WS_V0 + t] = a;
            ws[WS_W0 + t] = w;
        } else if (t == 64) {
            float cc = 0.f;
            for (int o = 0; o < 128; o++) cc += bk[o] * bq[o];
            ws[WS_C0] = cc;
        }
        if (t < 128) { ws[WS_S1 + t] = 0.f; ws[WS_S2 + t] = 0.f; }
    }
}

// ---------------- K3: wave-per-face attention -> agg [face,64] ----------------
__global__ __launch_bounds__(256) void k_attn(const float* __restrict__ feaT,
                                              const int* __restrict__ ring,
                                              const int* __restrict__ pool,
                                              const float* __restrict__ ws,
                                              float* __restrict__ agg_out) {
    int lane = threadIdx.x & 63;
    int wid  = (blockIdx.x * 256 + threadIdx.x) >> 6;
    int nw   = (gridDim.x * 256) >> 6;

    float Mreg[64];
#pragma unroll
    for (int j = 0; j < 64; j++) Mreg[j] = ws[WS_MT + j * 64 + lane];
    float v0 = ws[WS_V0 + lane];
    float w0 = ws[WS_W0 + lane];
    float c0 = ws[WS_C0];
    const float scale = 0.08838834764831845f;   // 1/sqrt(128)

    for (int face = wid; face < NFACE; face += nw) {
        int b  = face / FP;
        int fp = face - b * FP;
        int p  = pool[fp];
        float sf = feaT[((long)(b * F_ALL + p)) * 64 + lane];

        // s = w0 . self + c0
        float s = w0 * sf;
#pragma unroll
        for (int off = 32; off >= 1; off >>= 1) s += __shfl_xor(s, off, 64);
        s += c0;

        // u = M . self + v0
        float u0 = v0, u1 = 0.f, u2 = 0.f, u3 = 0.f;
#pragma unroll
        for (int j = 0; j < 64; j += 4) {
            u0 += Mreg[j + 0] * lanebc(sf, j + 0);
            u1 += Mreg[j + 1] * lanebc(sf, j + 1);
            u2 += Mreg[j + 2] * lanebc(sf, j + 2);
            u3 += Mreg[j + 3] * lanebc(sf, j + 3);
        }
        float u = (u0 + u1) + (u2 + u3);

        const int* rrow = ring + (long)face * KK;
        float nv[KK];
        float logit[KK + 1];
        {
            float l = u * sf;
#pragma unroll
            for (int off = 32; off >= 1; off >>= 1) l += __shfl_xor(l, off, 64);
            logit[0] = (l + s) * scale;
        }
#pragma unroll
        for (int k = 0; k < KK; k++) {
            int r = rrow[k];
            float n = feaT[((long)(b * F_ALL + r)) * 64 + lane];
            nv[k] = n;
            float l = u * n;
#pragma unroll
            for (int off = 32; off >= 1; off >>= 1) l += __shfl_xor(l, off, 64);
            logit[k + 1] = (l + s) * scale;
        }
        // softmax over 17 (redundant per-lane, values wave-uniform)
        float m = logit[0];
#pragma unroll
        for (int k = 1; k <= KK; k++) m = fmaxf(m, logit[k]);
        float den = 0.f;
#pragma unroll
        for (int k = 0; k <= KK; k++) { logit[k] = __expf(logit[k] - m); den += logit[k]; }
        float inv = 1.0f / den;

        float a = logit[0] * sf;
#pragma unroll
        for (int k = 0; k < KK; k++) a += logit[k + 1] * nv[k];
        agg_out[(long)face * 64 + lane] = a * inv;
    }
}

// ---------------- K4: y = Wc*agg + bc  (+ BN stat atomics) ----------------
__global__ __launch_bounds__(256) void k_mlp(const float* __restrict__ agg,
                                             const float* __restrict__ Wc,
                                             const float* __restrict__ bc,
                                             float* __restrict__ y,
                                             float* __restrict__ ws) {
    __shared__ __align__(16) float WcT[64 * 132];
    __shared__ __align__(16) float AgT[64 * 132];
    int tid = threadIdx.x;
    for (int i = tid; i < 128 * 64; i += 256) {
        int o = i >> 6, j = i & 63;
        WcT[j * 132 + o] = Wc[i];
    }
    int fbase = blockIdx.x * 128;
    for (int i = tid; i < 128 * 64; i += 256) {
        int f = i >> 6, j = i & 63;
        int fg = fbase + f;
        AgT[j * 132 + f] = (fg < NFACE) ? agg[(long)fg * 64 + j] : 0.f;
    }
    __syncthreads();

    int tx = tid & 15, ty = tid >> 4;
    float acc[8][8];
#pragma unroll
    for (int a = 0; a < 8; a++)
#pragma unroll
        for (int b = 0; b < 8; b++) acc[a][b] = 0.f;

    for (int j = 0; j < 64; j++) {
        float4 w0 = *(const float4*)&WcT[j * 132 + ty * 8];
        float4 w1 = *(const float4*)&WcT[j * 132 + ty * 8 + 4];
        float4 a0 = *(const float4*)&AgT[j * 132 + tx * 8];
        float4 a1 = *(const float4*)&AgT[j * 132 + tx * 8 + 4];
        float wv[8] = {w0.x, w0.y, w0.z, w0.w, w1.x, w1.y, w1.z, w1.w};
        float av[8] = {a0.x, a0.y, a0.z, a0.w, a1.x, a1.y, a1.z, a1.w};
#pragma unroll
        for (int oi = 0; oi < 8; oi++)
#pragma unroll
            for (int fi = 0; fi < 8; fi++) acc[oi][fi] += wv[oi] * av[fi];
    }

    int fg0 = fbase + tx * 8;
    float s1[8], s2[8];
#pragma unroll
    for (int oi = 0; oi < 8; oi++) { s1[oi] = 0.f; s2[oi] = 0.f; }

    if (fg0 < NFACE) {           // 8-run entirely valid (NFACE % 8 == 0)
        int b   = fg0 / FP;      // batch boundary is 8-aligned too
        int fp0 = fg0 - b * FP;
#pragma unroll
        for (int oi = 0; oi < 8; oi++) {
            int o = ty * 8 + oi;
            float bias = bc[o];
            float v[8];
#pragma unroll
            for (int fi = 0; fi < 8; fi++) {
                v[fi] = acc[oi][fi] + bias;
                s1[oi] += v[fi];
                s2[oi] += v[fi] * v[fi];
            }
            float* dst = y + ((long)(b * OO + o)) * FP + fp0;
            *(float4*)(dst)     = make_float4(v[0], v[1], v[2], v[3]);
            *(float4*)(dst + 4) = make_float4(v[4], v[5], v[6], v[7]);
        }
    }
    // reduce over tx (16-lane groups) then atomics
#pragma unroll
    for (int oi = 0; oi < 8; oi++) {
        float a1 = s1[oi], a2 = s2[oi];
#pragma unroll
        for (int off = 1; off < 16; off <<= 1) {
            a1 += __shfl_xor(a1, off, 64);
            a2 += __shfl_xor(a2, off, 64);
        }
        if (tx == 0) {
            int o = ty * 8 + oi;
            atomicAdd(&ws[WS_S1 + o], a1);
            atomicAdd(&ws[WS_S2 + o], a2);
        }
    }
}

// ---------------- K5: BN finalize + ReLU, in-place ----------------
__global__ __launch_bounds__(256) void k_bn(float* __restrict__ y,
                                            const float* __restrict__ ws,
                                            const float* __restrict__ gamma,
                                            const float* __restrict__ beta) {
    const float invN = 1.0f / (float)NFACE;
    long idx = ((long)blockIdx.x * 256 + threadIdx.x) * 4;
    if (idx >= NELEM) return;
    int o = (int)((idx / FP) & 127);
    float mean = ws[WS_S1 + o] * invN;
    float var  = ws[WS_S2 + o] * invN - mean * mean;
    float sc = rsqrtf(var + 1e-5f) * gamma[o];
    float sh = beta[o] - mean * sc;
    float4 v = *(float4*)(y + idx);
    v.x = fmaxf(v.x * sc + sh, 0.f);
    v.y = fmaxf(v.y * sc + sh, 0.f);
    v.z = fmaxf(v.z * sc + sh, 0.f);
    v.w = fmaxf(v.w * sc + sh, 0.f);
    *(float4*)(y + idx) = v;
}

extern "C" void kernel_launch(void* const* d_in, const int* in_sizes, int n_in,
                              void* d_out, int out_size, void* d_ws, size_t ws_size,
                              hipStream_t stream) {
    const float* fea  = (const float*)d_in[0];
    const int*   ring = (const int*)d_in[1];
    const int*   pool = (const int*)d_in[2];
    // d_in[3] pos_embed unused by reference
    const float* Wk = (const float*)d_in[4];
    const float* bk = (const float*)d_in[5];
    const float* Wq = (const float*)d_in[6];
    const float* bq = (const float*)d_in[7];
    const float* Wc = (const float*)d_in[8];
    const float* bc = (const float*)d_in[9];
    const float* gamma = (const float*)d_in[10];
    const float* beta  = (const float*)d_in[11];

    float* out  = (float*)d_out;
    float* ws   = (float*)d_ws;
    float* feaT = out;               // reuse d_out as feaT scratch (dead before K4)
    float* agg  = ws + WS_AGG;

    k_transpose<<<dim3(BB * 313), 256, 0, stream>>>(fea, feaT);
    k_precompute<<<16, 256, 0, stream>>>(Wk, bk, Wq, bq, ws);
    k_attn<<<1250, 256, 0, stream>>>(feaT, ring, pool, ws, agg);
    k_mlp<<<313, 256, 0, stream>>>(agg, Wc, bc, out, ws);
    k_bn<<<NELEM / 4 / 256, 256, 0, stream>>>(out, ws, gamma, beta);
}

// Round 2
// 239.909 us; speedup vs baseline: 1.0241x; 1.0241x over previous
//
#include <hip/hip_runtime.h>

#define F_ALL 20000
#define FP    10000
#define BB    4
#define CC    64
#define KK    16
#define OO    128
#define NFACE (BB*FP)        // 40000
#define NELEM (BB*OO*FP)     // 5,120,000

// workspace layout (float offsets)
#define WS_AGG  0
#define WS_MT   (NFACE*64)        // A^T: MT[j][i] = A[i][j], A = Wq^T Wk
#define WS_V0   (WS_MT + 4096)
#define WS_G    (WS_V0 + 64)      // Gram 64x64
#define WS_SUMA (WS_G + 4096)     // column sums of agg (64)
#define WS_SC   (WS_SUMA + 64)    // per-o BN scale (128)
#define WS_SH   (WS_SC + 128)     // per-o BN shift (128)

__device__ __forceinline__ float lanebc(float v, int l) {
    return __uint_as_float(__builtin_amdgcn_readlane(__float_as_uint(v), l));
}

template<int CTRL>
__device__ __forceinline__ float dppmov(float v) {
    return __int_as_float(__builtin_amdgcn_update_dpp(0, __float_as_int(v), CTRL, 0xF, 0xF, true));
}

// all-lane sum over 64 lanes: 4 DPP row_ror stages (VALU) + xor16 + xor32
__device__ __forceinline__ float wave_allsum(float x) {
    x += dppmov<0x121>(x);   // row_ror:1
    x += dppmov<0x122>(x);   // row_ror:2
    x += dppmov<0x124>(x);   // row_ror:4
    x += dppmov<0x128>(x);   // row_ror:8  -> each lane holds its 16-row sum
    x += __shfl_xor(x, 16, 64);
    x += __shfl_xor(x, 32, 64);
    return x;
}

// ---------------- K1: transpose fea [B,C,F] -> feaT [B,F,64] ----------------
__global__ __launch_bounds__(256) void k_transpose(const float* __restrict__ fea,
                                                   float* __restrict__ feaT) {
    __shared__ float tile[64][65];
    int bb = blockIdx.x / 313;
    int tb = blockIdx.x % 313;
    int fbase = tb * 64;
    int tid = threadIdx.x;
    int x  = tid & 63;
    int y0 = tid >> 6;
    int f = fbase + x;
    if (f < F_ALL) {
#pragma unroll
        for (int i = 0; i < 16; i++) {
            int c = y0 + i * 4;
            tile[c][x] = fea[((long)bb * CC + c) * F_ALL + f];
        }
    }
    __syncthreads();
#pragma unroll
    for (int i = 0; i < 16; i++) {
        int fr = y0 + i * 4;
        int ff = fbase + fr;
        if (ff < F_ALL)
            feaT[((long)bb * F_ALL + ff) * 64 + x] = tile[x][fr];
    }
}

// ---------------- K2: precompute A^T, v0; zero G / sumA ----------------
__global__ __launch_bounds__(256) void k_precompute(const float* __restrict__ Wk,
                                                    const float* __restrict__ bk,
                                                    const float* __restrict__ Wq,
                                                    float* __restrict__ ws) {
    int idx = blockIdx.x * 256 + threadIdx.x;   // 0..4095
    int j = idx >> 6, i = idx & 63;
    float acc = 0.f;
#pragma unroll 8
    for (int o = 0; o < 128; o++) acc += Wq[o * 64 + i] * Wk[o * 64 + j];
    ws[WS_MT + idx] = acc;                       // MT[j][i] = A[i][j]
    ws[WS_G + idx] = 0.f;
    if (blockIdx.x == 0) {
        int t = threadIdx.x;
        if (t < 64) {
            float a = 0.f;
            for (int o = 0; o < 128; o++) a += Wq[o * 64 + t] * bk[o];
            ws[WS_V0 + t] = a;
            ws[WS_SUMA + t] = 0.f;
        }
    }
}

// ---------------- K3: wave-per-face attention -> agg [face,64] ----------------
__global__ __launch_bounds__(256) void k_attn(const float* __restrict__ feaT,
                                              const int* __restrict__ ring,
                                              const int* __restrict__ pool,
                                              const float* __restrict__ ws,
                                              float* __restrict__ agg_out) {
    int lane = threadIdx.x & 63;
    int wid  = (blockIdx.x * 256 + threadIdx.x) >> 6;
    int nw   = (gridDim.x * 256) >> 6;

    float Mreg[64];
#pragma unroll
    for (int j = 0; j < 64; j++) Mreg[j] = ws[WS_MT + j * 64 + lane];  // A[lane][j]
    float v0 = ws[WS_V0 + lane];
    const float scale = 0.08838834764831845f;   // 1/sqrt(128)

    for (int face = wid; face < NFACE; face += nw) {
        int b  = face / FP;
        long rowbase = (long)b * F_ALL;
        int p  = pool[face - b * FP];
        float sf = feaT[(rowbase + p) * 64 + lane];

        // neighbor indices (64B-aligned int4 loads) + gathers issued early
        const int4* rr4 = (const int4*)(ring + (long)face * KK);
        int4 r0 = rr4[0], r1 = rr4[1], r2 = rr4[2], r3 = rr4[3];
        int ridx[KK] = {r0.x,r0.y,r0.z,r0.w, r1.x,r1.y,r1.z,r1.w,
                        r2.x,r2.y,r2.z,r2.w, r3.x,r3.y,r3.z,r3.w};
        float nv[KK];
#pragma unroll
        for (int k = 0; k < KK; k++)
            nv[k] = feaT[(rowbase + ridx[k]) * 64 + lane];

        // u = A . self + v0   (per-lane row of A in regs, self via readlane)
        float u0 = v0, u1 = 0.f, u2 = 0.f, u3 = 0.f;
#pragma unroll
        for (int j = 0; j < 64; j += 4) {
            u0 += Mreg[j + 0] * lanebc(sf, j + 0);
            u1 += Mreg[j + 1] * lanebc(sf, j + 1);
            u2 += Mreg[j + 2] * lanebc(sf, j + 2);
            u3 += Mreg[j + 3] * lanebc(sf, j + 3);
        }
        float u = (u0 + u1) + (u2 + u3);

        float logit[KK + 1];
        logit[0] = wave_allsum(u * sf) * scale;
#pragma unroll
        for (int k = 0; k < KK; k++)
            logit[k + 1] = wave_allsum(u * nv[k]) * scale;

        // softmax over 17 (redundant per-lane, values wave-uniform)
        float m = logit[0];
#pragma unroll
        for (int k = 1; k <= KK; k++) m = fmaxf(m, logit[k]);
        float den = 0.f;
#pragma unroll
        for (int k = 0; k <= KK; k++) { logit[k] = __expf(logit[k] - m); den += logit[k]; }
        float inv = 1.0f / den;

        float a = logit[0] * sf;
#pragma unroll
        for (int k = 0; k < KK; k++) a += logit[k + 1] * nv[k];
        agg_out[(long)face * 64 + lane] = a * inv;
    }
}

// ---------------- K4a: Gram G = sum_f a_f a_f^T, sumA = sum_f a_f ----------------
__global__ __launch_bounds__(256) void k_gram(const float* __restrict__ agg,
                                              float* __restrict__ ws) {
    __shared__ float lbuf[32 * 64];    // 8 KB face chunk
    int tid = threadIdx.x;
    int ti = tid & 15, tj = tid >> 4;  // 16x16 -> (i,j) 4x4 tiles
    int base = blockIdx.x * 160;

    float acc[4][4];
#pragma unroll
    for (int a = 0; a < 4; a++)
#pragma unroll
        for (int b = 0; b < 4; b++) acc[a][b] = 0.f;
    float gacc[4] = {0.f, 0.f, 0.f, 0.f};

    for (int c = 0; c < 5; c++) {
        for (int i = tid; i < 2048; i += 256)
            lbuf[i] = agg[((long)(base + c * 32)) * 64 + i];
        __syncthreads();
#pragma unroll 4
        for (int f = 0; f < 32; f++) {
            float4 ai = *(const float4*)&lbuf[f * 64 + ti * 4];
            float4 aj = *(const float4*)&lbuf[f * 64 + tj * 4];
            float av[4] = {ai.x, ai.y, ai.z, ai.w};
            float bv[4] = {aj.x, aj.y, aj.z, aj.w};
#pragma unroll
            for (int a = 0; a < 4; a++) {
#pragma unroll
                for (int b = 0; b < 4; b++) acc[a][b] += av[a] * bv[b];
                gacc[a] += av[a];
            }
        }
        __syncthreads();
    }
#pragma unroll
    for (int a = 0; a < 4; a++)
#pragma unroll
        for (int b = 0; b < 4; b++)
            atomicAdd(&ws[WS_G + (ti * 4 + a) * 64 + tj * 4 + b], acc[a][b]);
    if (ti == tj)
#pragma unroll
        for (int a = 0; a < 4; a++)
            atomicAdd(&ws[WS_SUMA + ti * 4 + a], gacc[a]);
}

// ---------------- K4b: BN stats -> per-o scale/shift ----------------
__global__ __launch_bounds__(256) void k_stats(const float* __restrict__ Wc,
                                               const float* __restrict__ bc,
                                               const float* __restrict__ gamma,
                                               const float* __restrict__ beta,
                                               float* __restrict__ ws) {
    __shared__ float Gs[4096];
    __shared__ float gs[64];
    __shared__ float qs[256];
    int tid = threadIdx.x;
    for (int i = tid; i < 4096; i += 256) Gs[i] = ws[WS_G + i];
    if (tid < 64) gs[tid] = ws[WS_SUMA + tid];
    __syncthreads();

    int o = tid & 127, h = tid >> 7;
    float w[64];
#pragma unroll
    for (int q = 0; q < 16; q++) {
        float4 t = *(const float4*)&Wc[o * 64 + q * 4];
        w[q * 4 + 0] = t.x; w[q * 4 + 1] = t.y; w[q * 4 + 2] = t.z; w[q * 4 + 3] = t.w;
    }
    float qp = 0.f;
    for (int i = h * 32; i < h * 32 + 32; i++) {
        float t = 0.f;
#pragma unroll
        for (int j = 0; j < 64; j++) t += Gs[i * 64 + j] * w[j];
        qp += Wc[o * 64 + i] * t;      // reload keeps index static in regs
    }
    qs[tid] = qp;
    __syncthreads();
    if (h == 0) {
        const float invN = 1.0f / (float)NFACE;
        float qform = qs[o] + qs[o + 128];
        float md = 0.f;
#pragma unroll
        for (int j = 0; j < 64; j++) md += gs[j] * w[j];
        float bco = bc[o];
        float mean = md * invN + bco;
        float ey2  = (qform + 2.f * bco * md) * invN + bco * bco;
        float var  = ey2 - mean * mean;
        float sc   = gamma[o] * rsqrtf(var + 1e-5f);
        ws[WS_SC + o] = sc;
        ws[WS_SH + o] = beta[o] + (bco - mean) * sc;   // bc folded into shift
    }
}

// ---------------- K5: out = relu((Wc*agg)*sc + sh)  [B,O,Fp] ----------------
__global__ __launch_bounds__(256) void k_out(const float* __restrict__ agg,
                                             const float* __restrict__ Wc,
                                             const float* __restrict__ ws,
                                             float* __restrict__ out) {
    __shared__ __align__(16) float WcT[64 * 132];   // [j][o]
    __shared__ __align__(16) float AgT[64 * 68];    // [j][f]
    int tid = threadIdx.x;
    int fbase = blockIdx.x * 64;
    for (int i = tid; i < 128 * 64; i += 256) {
        int o = i >> 6, j = i & 63;
        WcT[j * 132 + o] = Wc[i];
    }
    for (int i = tid; i < 64 * 64; i += 256) {
        int f = i >> 6, j = i & 63;
        AgT[j * 68 + f] = agg[((long)(fbase + f)) * 64 + j];
    }
    __syncthreads();

    int tx = tid & 15, ty = tid >> 4;   // tx: 4 faces, ty: 8 outputs
    float acc[8][4];
#pragma unroll
    for (int a = 0; a < 8; a++)
#pragma unroll
        for (int b = 0; b < 4; b++) acc[a][b] = 0.f;

    for (int j = 0; j < 64; j++) {
        float4 w0 = *(const float4*)&WcT[j * 132 + ty * 8];
        float4 w1 = *(const float4*)&WcT[j * 132 + ty * 8 + 4];
        float4 a0 = *(const float4*)&AgT[j * 68 + tx * 4];
        float wv[8] = {w0.x, w0.y, w0.z, w0.w, w1.x, w1.y, w1.z, w1.w};
        float av[4] = {a0.x, a0.y, a0.z, a0.w};
#pragma unroll
        for (int oi = 0; oi < 8; oi++)
#pragma unroll
            for (int fi = 0; fi < 4; fi++) acc[oi][fi] += wv[oi] * av[fi];
    }

    int fg0 = fbase + tx * 4;
    int b   = fg0 / FP;
    int fp0 = fg0 - b * FP;             // batch boundary (10000) is 4-aligned
#pragma unroll
    for (int oi = 0; oi < 8; oi++) {
        int o = ty * 8 + oi;
        float sc = ws[WS_SC + o];
        float sh = ws[WS_SH + o];
        float4 v;
        v.x = fmaxf(acc[oi][0] * sc + sh, 0.f);
        v.y = fmaxf(acc[oi][1] * sc + sh, 0.f);
        v.z = fmaxf(acc[oi][2] * sc + sh, 0.f);
        v.w = fmaxf(acc[oi][3] * sc + sh, 0.f);
        *(float4*)&out[((long)(b * OO + o)) * FP + fp0] = v;
    }
}

extern "C" void kernel_launch(void* const* d_in, const int* in_sizes, int n_in,
                              void* d_out, int out_size, void* d_ws, size_t ws_size,
                              hipStream_t stream) {
    const float* fea  = (const float*)d_in[0];
    const int*   ring = (const int*)d_in[1];
    const int*   pool = (const int*)d_in[2];
    const float* Wk = (const float*)d_in[4];
    const float* bk = (const float*)d_in[5];
    const float* Wq = (const float*)d_in[6];
    // bq unused (cancels in softmax)
    const float* Wc = (const float*)d_in[8];
    const float* bc = (const float*)d_in[9];
    const float* gamma = (const float*)d_in[10];
    const float* beta  = (const float*)d_in[11];

    float* out  = (float*)d_out;
    float* ws   = (float*)d_ws;
    float* feaT = out;               // d_out reused as feaT scratch (dead before k_out)
    float* agg  = ws + WS_AGG;

    k_transpose <<<dim3(BB * 313), 256, 0, stream>>>(fea, feaT);
    k_precompute<<<16,   256, 0, stream>>>(Wk, bk, Wq, ws);
    k_attn      <<<2500, 256, 0, stream>>>(feaT, ring, pool, ws, agg);
    k_gram      <<<250,  256, 0, stream>>>(agg, ws);
    k_stats     <<<1,    256, 0, stream>>>(Wc, bc, gamma, beta, ws);
    k_out       <<<625,  256, 0, stream>>>(agg, Wc, ws, out);
}

// Round 3
// 195.477 us; speedup vs baseline: 1.2569x; 1.2273x over previous
//
#include <hip/hip_runtime.h>

#define F_ALL 20000
#define FP    10000
#define BB    4
#define CC    64
#define KK    16
#define OO    128
#define NFACE (BB*FP)        // 40000
#define NELEM (BB*OO*FP)     // 5,120,000
#define NGRAMB 125           // gram partial blocks (125*320 = 40000 faces)

// workspace layout (float offsets) — total ~10.3 MB
#define WS_AGG  0                  // U (from k_qvec) then agg (k_attn overwrites row-wise)
#define WS_MT   (NFACE*64)         // A^T layout: MT[j*64+i] = A[i][j], A = Wq^T Wk
#define WS_V0   (WS_MT + 4096)
#define WS_G    (WS_V0 + 64)       // final Gram 64x64
#define WS_SUMA (WS_G + 4096)      // final column sums of agg (64)
#define WS_SC   (WS_SUMA + 64)     // per-o BN scale (128)
#define WS_SH   (WS_SC + 128)      // per-o BN shift (128)

template<int CTRL>
__device__ __forceinline__ float dpp_add(float x) {
    return x + __int_as_float(__builtin_amdgcn_update_dpp(0, __float_as_int(x), CTRL, 0xF, 0xF, true));
}
// all-reduce sum within each 16-lane row (4 VALU DPP stages)
__device__ __forceinline__ float sum16(float x) {
    x = dpp_add<0x121>(x);   // row_ror:1
    x = dpp_add<0x122>(x);   // row_ror:2
    x = dpp_add<0x124>(x);   // row_ror:4
    x = dpp_add<0x128>(x);   // row_ror:8
    return x;
}

// ---------------- K1: transpose fea [B,C,F] -> feaT [B,F,64] ----------------
__global__ __launch_bounds__(256) void k_transpose(const float* __restrict__ fea,
                                                   float* __restrict__ feaT) {
    __shared__ float tile[64][65];
    int bb = blockIdx.x / 313;
    int tb = blockIdx.x % 313;
    int fbase = tb * 64;
    int tid = threadIdx.x;
    int x  = tid & 63;
    int y0 = tid >> 6;
    int f = fbase + x;
    if (f < F_ALL) {
#pragma unroll
        for (int i = 0; i < 16; i++) {
            int c = y0 + i * 4;
            tile[c][x] = fea[((long)bb * CC + c) * F_ALL + f];
        }
    }
    __syncthreads();
#pragma unroll
    for (int i = 0; i < 16; i++) {
        int fr = y0 + i * 4;
        int ff = fbase + fr;
        if (ff < F_ALL)
            feaT[((long)bb * F_ALL + ff) * 64 + x] = tile[x][fr];
    }
}

// ---------------- K2: precompute A^T (MT[j][i]=A[i][j]) and v0 ----------------
__global__ __launch_bounds__(256) void k_precompute(const float* __restrict__ Wk,
                                                    const float* __restrict__ bk,
                                                    const float* __restrict__ Wq,
                                                    float* __restrict__ ws) {
    int idx = blockIdx.x * 256 + threadIdx.x;   // 0..4095
    int j = idx >> 6, i = idx & 63;
    float acc = 0.f;
#pragma unroll 8
    for (int o = 0; o < 128; o++) acc += Wq[o * 64 + i] * Wk[o * 64 + j];
    ws[WS_MT + idx] = acc;                       // MT[j*64+i] = A[i][j]
    if (blockIdx.x == 0 && threadIdx.x < 64) {
        int t = threadIdx.x;
        float a = 0.f;
        for (int o = 0; o < 128; o++) a += Wq[o * 64 + t] * bk[o];
        ws[WS_V0 + t] = a;
    }
}

// ---------------- K3: U = selfGather * A + v0  (GEMM, 64 faces/block) ----------------
__global__ __launch_bounds__(256) void k_qvec(const float* __restrict__ feaT,
                                              const int* __restrict__ pool,
                                              float* __restrict__ ws) {
    __shared__ float At[4096];        // At[j*64+i] = A[i][j]
    __shared__ float Sf[64 * 65];     // gathered self rows, padded stride 65
    int tid = threadIdx.x;
    int fbase = blockIdx.x * 64;

    for (int i = tid; i < 4096; i += 256) At[i] = ws[WS_MT + i];
    {
        int r = tid >> 2;                  // row 0..63
        int face = fbase + r;
        int b = face / FP;
        int fp = face - b * FP;
        int p = pool[fp];
        const float* src = feaT + ((long)(b * F_ALL + p)) * 64;
        int off = (tid & 3) * 4;
#pragma unroll
        for (int it = 0; it < 4; it++, off += 16) {
            float4 v = *(const float4*)(src + off);
            Sf[r * 65 + off + 0] = v.x;
            Sf[r * 65 + off + 1] = v.y;
            Sf[r * 65 + off + 2] = v.z;
            Sf[r * 65 + off + 3] = v.w;
        }
    }
    __syncthreads();

    int ti = tid & 15, tj = tid >> 4;  // ti: 4 faces, tj: 4 outputs
    int f0 = ti * 4, o0 = tj * 4;
    float4 v0 = *(const float4*)&ws[WS_V0 + o0];
    float acc[4][4];
#pragma unroll
    for (int a = 0; a < 4; a++) {
        acc[a][0] = v0.x; acc[a][1] = v0.y; acc[a][2] = v0.z; acc[a][3] = v0.w;
    }
    for (int j = 0; j < 64; j++) {
        float4 wv = *(const float4*)&At[j * 64 + o0];
#pragma unroll
        for (int a = 0; a < 4; a++) {
            float av = Sf[(f0 + a) * 65 + j];
            acc[a][0] += av * wv.x;
            acc[a][1] += av * wv.y;
            acc[a][2] += av * wv.z;
            acc[a][3] += av * wv.w;
        }
    }
#pragma unroll
    for (int a = 0; a < 4; a++)
        *(float4*)&ws[WS_AGG + ((long)(fbase + f0 + a)) * 64 + o0] =
            make_float4(acc[a][0], acc[a][1], acc[a][2], acc[a][3]);
}

// ---------------- K4: attention, 16 lanes/face, wave = 4 faces ----------------
__global__ __launch_bounds__(256) void k_attn(const float* __restrict__ feaT,
                                              const int* __restrict__ ring,
                                              const int* __restrict__ pool,
                                              float* __restrict__ ws) {
    int tid = threadIdx.x;
    int lane = tid & 63;
    int il = lane & 15;            // channel group
    int c4 = il * 4;
    int face = blockIdx.x * 16 + (tid >> 4);
    int b  = face / FP;
    int fp = face - b * FP;
    const float* fb = feaT + ((long)b * F_ALL) * 64 + c4;
    const float scale = 0.08838834764831845f;   // 1/sqrt(128)

    int p = pool[fp];
    float4 sf = *(const float4*)(fb + (long)p * 64);
    float4 u  = *(const float4*)&ws[WS_AGG + (long)face * 64 + c4];

    int rv = ring[face * KK + il];              // lane il holds k=il index
    float4 nv[KK];
#pragma unroll
    for (int k = 0; k < KK; k++) {
        int rk = __shfl(rv, (lane & 48) | k, 64);
        nv[k] = *(const float4*)(fb + (long)rk * 64);
    }

    float l[KK + 1];
    l[0] = sum16(u.x * sf.x + u.y * sf.y + u.z * sf.z + u.w * sf.w) * scale;
#pragma unroll
    for (int k = 0; k < KK; k++)
        l[k + 1] = sum16(u.x * nv[k].x + u.y * nv[k].y + u.z * nv[k].z + u.w * nv[k].w) * scale;

    float m = l[0];
#pragma unroll
    for (int k = 1; k <= KK; k++) m = fmaxf(m, l[k]);
    float den = 0.f;
#pragma unroll
    for (int k = 0; k <= KK; k++) { l[k] = __expf(l[k] - m); den += l[k]; }
    float inv = 1.0f / den;

    float4 a;
    a.x = l[0] * sf.x; a.y = l[0] * sf.y; a.z = l[0] * sf.z; a.w = l[0] * sf.w;
#pragma unroll
    for (int k = 0; k < KK; k++) {
        a.x += l[k + 1] * nv[k].x;
        a.y += l[k + 1] * nv[k].y;
        a.z += l[k + 1] * nv[k].z;
        a.w += l[k + 1] * nv[k].w;
    }
    a.x *= inv; a.y *= inv; a.z *= inv; a.w *= inv;
    *(float4*)&ws[WS_AGG + (long)face * 64 + c4] = a;   // alias: own row read above
}

// ---------------- K5a: Gram partials (privatized, no atomics) ----------------
__global__ __launch_bounds__(256) void k_gram(const float* __restrict__ agg,
                                              float* __restrict__ gp,
                                              float* __restrict__ sap) {
    __shared__ float lbuf[4096];
    int tid = threadIdx.x;
    int ti = tid & 15, tj = tid >> 4;
    float acc[4][4];
#pragma unroll
    for (int a = 0; a < 4; a++)
#pragma unroll
        for (int b = 0; b < 4; b++) acc[a][b] = 0.f;
    float gacc[4] = {0.f, 0.f, 0.f, 0.f};

    for (int c = 0; c < 5; c++) {
        int fbase = blockIdx.x * 320 + c * 64;
        const float4* src = (const float4*)(agg + (long)fbase * 64);
        float4* dst = (float4*)lbuf;
        for (int i = tid; i < 1024; i += 256) dst[i] = src[i];
        __syncthreads();
#pragma unroll 4
        for (int f = 0; f < 64; f++) {
            float4 av = *(const float4*)&lbuf[f * 64 + ti * 4];
            float4 bv = *(const float4*)&lbuf[f * 64 + tj * 4];
            float avv[4] = {av.x, av.y, av.z, av.w};
            float bvv[4] = {bv.x, bv.y, bv.z, bv.w};
#pragma unroll
            for (int a = 0; a < 4; a++) {
#pragma unroll
                for (int b = 0; b < 4; b++) acc[a][b] += avv[a] * bvv[b];
                gacc[a] += avv[a];
            }
        }
        __syncthreads();
    }
#pragma unroll
    for (int a = 0; a < 4; a++)
        *(float4*)&gp[(long)blockIdx.x * 4096 + (ti * 4 + a) * 64 + tj * 4] =
            make_float4(acc[a][0], acc[a][1], acc[a][2], acc[a][3]);
    if (tj == 0)
        *(float4*)&sap[blockIdx.x * 64 + ti * 4] =
            make_float4(gacc[0], gacc[1], gacc[2], gacc[3]);
}

// ---------------- K5b: reduce partials -> final G, sumA ----------------
__global__ __launch_bounds__(256) void k_gsum(const float* __restrict__ gp,
                                              const float* __restrict__ sap,
                                              float* __restrict__ ws) {
    if (blockIdx.x < 16) {
        int e = blockIdx.x * 256 + threadIdx.x;
        float s = 0.f;
#pragma unroll 5
        for (int p = 0; p < NGRAMB; p++) s += gp[(long)p * 4096 + e];
        ws[WS_G + e] = s;
    } else if (threadIdx.x < 64) {
        float s = 0.f;
#pragma unroll 5
        for (int p = 0; p < NGRAMB; p++) s += sap[p * 64 + threadIdx.x];
        ws[WS_SUMA + threadIdx.x] = s;
    }
}

// ---------------- K5c: BN stats -> per-o scale/shift ----------------
__global__ __launch_bounds__(256) void k_stats(const float* __restrict__ Wc,
                                               const float* __restrict__ bc,
                                               const float* __restrict__ gamma,
                                               const float* __restrict__ beta,
                                               float* __restrict__ ws) {
    __shared__ float Gs[4096];
    __shared__ float gs[64];
    __shared__ float qs[256];
    int tid = threadIdx.x;
    for (int i = tid; i < 4096; i += 256) Gs[i] = ws[WS_G + i];
    if (tid < 64) gs[tid] = ws[WS_SUMA + tid];
    __syncthreads();

    int o = tid & 127, h = tid >> 7;
    float w[64];
#pragma unroll
    for (int q = 0; q < 16; q++) {
        float4 t = *(const float4*)&Wc[o * 64 + q * 4];
        w[q * 4 + 0] = t.x; w[q * 4 + 1] = t.y; w[q * 4 + 2] = t.z; w[q * 4 + 3] = t.w;
    }
    float qp = 0.f;
    for (int i = h * 32; i < h * 32 + 32; i++) {
        float t = 0.f;
#pragma unroll
        for (int j = 0; j < 64; j++) t += Gs[i * 64 + j] * w[j];
        qp += Wc[o * 64 + i] * t;
    }
    qs[tid] = qp;
    __syncthreads();
    if (h == 0) {
        const float invN = 1.0f / (float)NFACE;
        float qform = qs[o] + qs[o + 128];
        float md = 0.f;
#pragma unroll
        for (int j = 0; j < 64; j++) md += gs[j] * w[j];
        float bco = bc[o];
        float mean = md * invN + bco;
        float ey2  = (qform + 2.f * bco * md) * invN + bco * bco;
        float var  = ey2 - mean * mean;
        float sc   = gamma[o] * rsqrtf(var + 1e-5f);
        ws[WS_SC + o] = sc;
        ws[WS_SH + o] = beta[o] + (bco - mean) * sc;
    }
}

// ---------------- K6: out = relu((Wc*agg)*sc + sh)  [B,O,Fp] ----------------
__global__ __launch_bounds__(256) void k_out(const float* __restrict__ agg,
                                             const float* __restrict__ Wc,
                                             const float* __restrict__ ws,
                                             float* __restrict__ out) {
    __shared__ __align__(16) float WcT[64 * 132];   // [j][o]
    __shared__ __align__(16) float AgT[64 * 68];    // [j][f]
    int tid = threadIdx.x;
    int fbase = blockIdx.x * 64;
    for (int i = tid; i < 128 * 64; i += 256) {
        int o = i >> 6, j = i & 63;
        WcT[j * 132 + o] = Wc[i];
    }
    for (int i = tid; i < 64 * 64; i += 256) {
        int f = i >> 6, j = i & 63;
        AgT[j * 68 + f] = agg[((long)(fbase + f)) * 64 + j];
    }
    __syncthreads();

    int tx = tid & 15, ty = tid >> 4;   // tx: 4 faces, ty: 8 outputs
    float acc[8][4];
#pragma unroll
    for (int a = 0; a < 8; a++)
#pragma unroll
        for (int b = 0; b < 4; b++) acc[a][b] = 0.f;

    for (int j = 0; j < 64; j++) {
        float4 w0 = *(const float4*)&WcT[j * 132 + ty * 8];
        float4 w1 = *(const float4*)&WcT[j * 132 + ty * 8 + 4];
        float4 a0 = *(const float4*)&AgT[j * 68 + tx * 4];
        float wv[8] = {w0.x, w0.y, w0.z, w0.w, w1.x, w1.y, w1.z, w1.w};
        float av[4] = {a0.x, a0.y, a0.z, a0.w};
#pragma unroll
        for (int oi = 0; oi < 8; oi++)
#pragma unroll
            for (int fi = 0; fi < 4; fi++) acc[oi][fi] += wv[oi] * av[fi];
    }

    int fg0 = fbase + tx * 4;
    int b   = fg0 / FP;
    int fp0 = fg0 - b * FP;             // batch boundary (10000) is 4-aligned
#pragma unroll
    for (int oi = 0; oi < 8; oi++) {
        int o = ty * 8 + oi;
        float sc = ws[WS_SC + o];
        float sh = ws[WS_SH + o];
        float4 v;
        v.x = fmaxf(acc[oi][0] * sc + sh, 0.f);
        v.y = fmaxf(acc[oi][1] * sc + sh, 0.f);
        v.z = fmaxf(acc[oi][2] * sc + sh, 0.f);
        v.w = fmaxf(acc[oi][3] * sc + sh, 0.f);
        *(float4*)&out[((long)(b * OO + o)) * FP + fp0] = v;
    }
}

extern "C" void kernel_launch(void* const* d_in, const int* in_sizes, int n_in,
                              void* d_out, int out_size, void* d_ws, size_t ws_size,
                              hipStream_t stream) {
    const float* fea  = (const float*)d_in[0];
    const int*   ring = (const int*)d_in[1];
    const int*   pool = (const int*)d_in[2];
    const float* Wk = (const float*)d_in[4];
    const float* bk = (const float*)d_in[5];
    const float* Wq = (const float*)d_in[6];
    // bq unused (its logit terms are constant per-face -> cancel in softmax)
    const float* Wc = (const float*)d_in[8];
    const float* bc = (const float*)d_in[9];
    const float* gamma = (const float*)d_in[10];
    const float* beta  = (const float*)d_in[11];

    float* out  = (float*)d_out;
    float* ws   = (float*)d_ws;
    float* feaT = out;                     // d_out[0..5.12M) = feaT (dead after k_attn)
    float* agg  = ws + WS_AGG;             // U, then agg (aliased row-wise in k_attn)
    float* gp   = out;                     // gram partials reuse d_out after feaT dies
    float* sap  = out + NGRAMB * 4096;

    k_transpose <<<dim3(BB * 313), 256, 0, stream>>>(fea, feaT);
    k_precompute<<<16,   256, 0, stream>>>(Wk, bk, Wq, ws);
    k_qvec      <<<625,  256, 0, stream>>>(feaT, pool, ws);
    k_attn      <<<2500, 256, 0, stream>>>(feaT, ring, pool, ws);
    k_gram      <<<NGRAMB, 256, 0, stream>>>(agg, gp, sap);
    k_gsum      <<<17,   256, 0, stream>>>(gp, sap, ws);
    k_stats     <<<1,    256, 0, stream>>>(Wc, bc, gamma, beta, ws);
    k_out       <<<625,  256, 0, stream>>>(agg, Wc, ws, out);
}